// Round 9
// baseline (272.472 us; speedup 1.0000x reference)
//
#include <hip/hip_runtime.h>
#include <hip/hip_bf16.h>

#define NN    100000
#define DF    64
#define NPB   16
#define NBLK  (NN / NPB)   // 6250 exact

typedef __bf16 bf16x8 __attribute__((ext_vector_type(8)));
typedef float  f32x4  __attribute__((ext_vector_type(4)));

// tanh-approx gelu, exp2-folded: x / (1 + 2^-(c1*x + c2*x^3))
__device__ __forceinline__ float gelu_f(float x) {
    float u2 = x * (2.302234849f + 0.102953097f * x * x);
    float s  = exp2f(-u2);
    return __fdividef(x, 1.0f + s);
}

__device__ __forceinline__ unsigned cvt_pk_bf16(float lo, float hi) {
    unsigned r;
    asm("v_cvt_pk_bf16_f32 %0, %1, %2" : "=v"(r) : "v"(lo), "v"(hi));
    return r;
}

__global__ __launch_bounds__(256, 6)
void it_fused(const float* __restrict__ y, const float* __restrict__ fy,
              const float* __restrict__ W0, const float* __restrict__ b0,
              const float* __restrict__ W1, const float* __restrict__ b1,
              const int* __restrict__ nbr, const int* __restrict__ splits,
              float* __restrict__ out)
{
    __shared__ __align__(16) float nodeacc[NPB][DF];        // 4 KB
    __shared__ __align__(16) int   nsL[4][64];              // 1 KB, packed nb<<4|sg
    __shared__ __align__(16) __bf16 aggW[4][64][8];         // 4 KB
    __shared__ __align__(16) __bf16 hL[4][16][DF];          // 8 KB h0 transpose buf
    __shared__ __align__(16) __bf16 w0lds[64][8];           // 1 KB: frag[feat=nt*16+c]
    __shared__ __align__(16) __bf16 w1lds[512][8];          // 8 KB: frag[kf*256+nt*64+lane]
    __shared__ float yselfL[NPB][3];
    __shared__ int   splitsL[NPB + 1];

    const int t  = threadIdx.x;
    const int n0 = blockIdx.x * NPB;

    // ---- prologue: stage splits, self-coords, weight fragments; zero accum ----
    if (t <= NPB) splitsL[t] = splits[n0 + t];
    if (t < NPB) {
        yselfL[t][0] = y[(n0 + t) * 3 + 0];
        yselfL[t][1] = y[(n0 + t) * 3 + 1];
        yselfL[t][2] = y[(n0 + t) * 3 + 2];
    }
    for (int i = t; i < NPB * DF / 4; i += 256)
        ((float4*)nodeacc)[i] = make_float4(0, 0, 0, 0);
    // W1 fragments: lane l of wave reads w1lds[kf*256+nt*64+l] -> W1[(kf*32+(l>>4)*8+j)][ (l&15)*4+nt ]
    for (int i = t; i < 512; i += 256) {
        const int kf = i >> 8, nt = (i >> 6) & 3, l = i & 63;
        __bf16 tmp[8];
        #pragma unroll
        for (int j = 0; j < 8; j++)
            tmp[j] = (__bf16)W1[(kf * 32 + (l >> 4) * 8 + j) * DF + (l & 15) * 4 + nt];
        *(bf16x8*)&w1lds[i][0] = *(const bf16x8*)tmp;
    }
    // W0ext fragments (feat = t): rows 0..5 = W0, row 6 = b0 (bias via agg[6]=1), row 7 = 0
    if (t < 64) {
        __bf16 tmp[8];
        #pragma unroll
        for (int j = 0; j < 6; j++) tmp[j] = (__bf16)W0[j * DF + t];
        tmp[6] = (__bf16)b0[t];
        tmp[7] = (__bf16)0.0f;
        *(bf16x8*)&w0lds[t][0] = *(const bf16x8*)tmp;
    }
    __syncthreads();

    const int e_begin = splitsL[0];
    const int e_end   = splitsL[NPB];
    const int lane = t & 63;
    const int wv   = t >> 6;
    const int col  = lane & 15;
    const int kg   = lane >> 4;

    const float4 b1v = *(const float4*)(b1 + col * 4);   // b1[col*4+nt]

    __bf16* const hw = &hL[wv][0][0];
    const int swz = (col & 7) << 4;
    const char* const w1base = (const char*)&w1lds[0][0] + lane * 16;

    // ---- barrier-free main loop: each wave owns 64-edge batches, stride 256 ----
    for (int ebase = e_begin + wv * 64; ebase < e_end; ebase += 256) {
        const int e = ebase + lane;

        int nb = 0;
        if (e < e_end) nb = nbr[e];
        int sg = 0;
        #pragma unroll
        for (int step = 8; step >= 1; step >>= 1)
            if (splitsL[sg + step] <= e) sg += step;   // e>=e_end -> 15, masked later

        nsL[wv][lane] = (nb << 4) | sg;
        bf16x8 ag = {};
        if (e < e_end) {
            ag[0] = (__bf16)y[nb * 3 + 0];
            ag[1] = (__bf16)y[nb * 3 + 1];
            ag[2] = (__bf16)y[nb * 3 + 2];
            ag[3] = (__bf16)yselfL[sg][0];
            ag[4] = (__bf16)yselfL[sg][1];
            ag[5] = (__bf16)yselfL[sg][2];
            ag[6] = (__bf16)1.0f;            // bias slot (W0ext row 6 = b0)
        }
        *(bf16x8*)&aggW[wv][lane][0] = ag;

        #pragma unroll
        for (int g = 0; g < 4; g++) {
            const int gb = g * 16;
            const int qi = gb + kg * 4;
            const int4 q = *(const int4*)&nsL[wv][qi];

            bf16x8 a0 = {};
            if (kg == 0) a0 = *(const bf16x8*)&aggW[wv][gb + col][0];

            // layer 0 SWAPPED: lane holds h0^T[feat nt*16+kg*4+r][edge=col]
            // A-frag (W0ext) nonzero only for kg==0 (k=0..7)
            f32x4 acc0[4] = {};
            #pragma unroll
            for (int nt = 0; nt < 4; nt++) {
                bf16x8 w0t = {};
                if (kg == 0) w0t = *(const bf16x8*)&w0lds[nt * 16 + col][0];
                acc0[nt] = __builtin_amdgcn_mfma_f32_16x16x32_bf16(w0t, a0, acc0[nt], 0, 0, 0);
            }

            // gelu + pack + 4x ds_write_b64 into hL[edge=col][feature] (swizzled)
            #pragma unroll
            for (int nt = 0; nt < 4; nt++) {
                const unsigned p0 = cvt_pk_bf16(gelu_f(acc0[nt][0]), gelu_f(acc0[nt][1]));
                const unsigned p1 = cvt_pk_bf16(gelu_f(acc0[nt][2]), gelu_f(acc0[nt][3]));
                const int off = col * 128 + ((nt * 32 + kg * 8) ^ swz);
                *(int2*)((char*)hw + off) = make_int2((int)p0, (int)p1);
            }
            bf16x8 af1[2];
            #pragma unroll
            for (int kf = 0; kf < 2; kf++) {
                const int off = col * 128 + ((kf * 64 + kg * 16) ^ swz);
                af1[kf] = *(const bf16x8*)((const char*)hw + off);
            }

            // layer 1: D1[edge=kg*4+r][c=col*4+nt], fp32 accum; W1 frags from LDS
            f32x4 acc[4] = {};
            #pragma unroll
            for (int nt = 0; nt < 4; nt++) {
                #pragma unroll
                for (int kf = 0; kf < 2; kf++) {
                    const bf16x8 w1t = *(const bf16x8*)(w1base + (kf * 256 + nt * 64) * 16);
                    acc[nt] = __builtin_amdgcn_mfma_f32_16x16x32_bf16(af1[kf], w1t, acc[nt], 0, 0, 0);
                }
            }

            // gate by f_y[nbr], segmented-reduce into LDS node accumulators
            const int s0 = q.x & 15, s1 = q.y & 15, s2 = q.z & 15, s3 = q.w & 15;
            const float4 fv0 = *(const float4*)(fy + (q.x >> 4) * DF + col * 4);
            const float4 fv1 = *(const float4*)(fy + (q.y >> 4) * DF + col * 4);
            const float4 fv2 = *(const float4*)(fy + (q.z >> 4) * DF + col * 4);
            const float4 fv3 = *(const float4*)(fy + (q.w >> 4) * DF + col * 4);

            const int rem = e_end - (ebase + qi);   // edge r valid iff r < rem
            #pragma unroll
            for (int nt = 0; nt < 4; nt++) {
                const int   c  = col * 4 + nt;
                const float bb = (&b1v.x)[nt];
                float v0 = (0 < rem) ? (acc[nt][0] + bb) * (&fv0.x)[nt] : 0.0f;
                float v1 = (1 < rem) ? (acc[nt][1] + bb) * (&fv1.x)[nt] : 0.0f;
                float v2 = (2 < rem) ? (acc[nt][2] + bb) * (&fv2.x)[nt] : 0.0f;
                float v3 = (3 < rem) ? (acc[nt][3] + bb) * (&fv3.x)[nt] : 0.0f;
                if (s0 == s3) {   // monotone seg -> all four equal: merged single atomic
                    unsafeAtomicAdd(&nodeacc[s0][c], ((v0 + v1) + (v2 + v3)));
                } else {
                    unsafeAtomicAdd(&nodeacc[s0][c], v0);
                    unsafeAtomicAdd(&nodeacc[s1][c], v1);
                    unsafeAtomicAdd(&nodeacc[s2][c], v2);
                    unsafeAtomicAdd(&nodeacc[s3][c], v3);
                }
            }
        }
    }

    __syncthreads();

    // ---- Epilogue: mean and store (each node owned by exactly this block) ----
    for (int i = t; i < NPB * (DF / 4); i += 256) {
        const int node = i >> 4;
        const int cnt  = splitsL[node + 1] - splitsL[node];
        const float inv = (cnt > 0) ? __fdividef(1.0f, (float)cnt) : 0.0f;
        float4 v = ((const float4*)nodeacc)[i];
        v.x *= inv; v.y *= inv; v.z *= inv; v.w *= inv;
        ((float4*)out)[n0 * (DF / 4) + i] = v;
    }
}

extern "C" void kernel_launch(void* const* d_in, const int* in_sizes, int n_in,
                              void* d_out, int out_size, void* d_ws, size_t ws_size,
                              hipStream_t stream) {
    const float* y   = (const float*)d_in[0];
    const float* fyv = (const float*)d_in[1];
    const float* W0  = (const float*)d_in[2];
    const float* b0  = (const float*)d_in[3];
    const float* W1  = (const float*)d_in[4];
    const float* b1  = (const float*)d_in[5];
    const int*   nb  = (const int*)d_in[6];   // harness delivers integer inputs as int32
    const int*   sp  = (const int*)d_in[7];
    it_fused<<<NBLK, 256, 0, stream>>>(y, fyv, W0, b0, W1, b1, nb, sp, (float*)d_out);
}

// Round 10
// 270.868 us; speedup vs baseline: 1.0059x; 1.0059x over previous
//
#include <hip/hip_runtime.h>
#include <hip/hip_bf16.h>

#define NN    100000
#define DF    64
#define NPB   32
#define NBLK  (NN / NPB)   // 3125 exact

typedef __bf16 bf16x8 __attribute__((ext_vector_type(8)));
typedef float  f32x4  __attribute__((ext_vector_type(4)));

// tanh-approx gelu, exp2-folded: x / (1 + 2^-(c1*x + c2*x^3))
__device__ __forceinline__ float gelu_f(float x) {
    float u2 = x * (2.302234849f + 0.102953097f * x * x);
    float s  = exp2f(-u2);
    return __fdividef(x, 1.0f + s);
}

__device__ __forceinline__ unsigned cvt_pk_bf16(float lo, float hi) {
    unsigned r;
    asm("v_cvt_pk_bf16_f32 %0, %1, %2" : "=v"(r) : "v"(lo), "v"(hi));
    return r;
}

__global__ void it_fused(const float* __restrict__ y, const float* __restrict__ fy,
              const float* __restrict__ W0, const float* __restrict__ b0,
              const float* __restrict__ W1, const float* __restrict__ b1,
              const int* __restrict__ nbr, const int* __restrict__ splits,
              float* __restrict__ out)
{
    __shared__ int   splitsL[NPB + 1];
    __shared__ float yselfL[NPB][3];
    __shared__ float nodeacc[NPB][DF];                       // 8 KB
    __shared__ __align__(16) int nsL[4][64];                 // packed nb*32+sg, 1 KB
    __shared__ __align__(16) __bf16 aggW[4][64][8];          // 4 KB
    __shared__ __align__(16) __bf16 hL[4][16][DF];           // 8 KB h0 transpose buf

    const int t  = threadIdx.x;
    const int n0 = blockIdx.x * NPB;

    if (t <= NPB) splitsL[t] = splits[n0 + t];
    if (t < NPB) {
        yselfL[t][0] = y[(n0 + t) * 3 + 0];
        yselfL[t][1] = y[(n0 + t) * 3 + 1];
        yselfL[t][2] = y[(n0 + t) * 3 + 2];
    }
    for (int i = t; i < NPB * DF / 4; i += 256) ((float4*)nodeacc)[i] = make_float4(0, 0, 0, 0);
    __syncthreads();

    const int e_begin = splitsL[0];
    const int e_end   = splitsL[NPB];
    const int lane = t & 63;
    const int wv   = t >> 6;
    const int col  = lane & 15;
    const int kg   = lane >> 4;

    // ---- weight fragments (register-resident) ----
    // Layer 0 as MFMA *A* (swapped): A[m=feat nt*16+col][k=kg*8+j] = W0ext[k][feat];
    // row 6 = b0 (bias via agg[6]=1), rows 7..31 = 0.
    bf16x8 w0f[4];
    #pragma unroll
    for (int nt = 0; nt < 4; nt++)
        #pragma unroll
        for (int j = 0; j < 8; j++) {
            const int k = kg * 8 + j;
            float v = 0.0f;
            if (k < 6)       v = W0[k * DF + nt * 16 + col];
            else if (k == 6) v = b0[nt * 16 + col];
            w0f[nt][j] = (__bf16)v;
        }
    // Layer 1 B-fragments, column-permuted c = col*4 + nt
    bf16x8 w1f[4][2];
    float  b1r[4];
    #pragma unroll
    for (int nt = 0; nt < 4; nt++) {
        b1r[nt] = b1[col * 4 + nt];
        #pragma unroll
        for (int kf = 0; kf < 2; kf++)
            #pragma unroll
            for (int j = 0; j < 8; j++)
                w1f[nt][kf][j] = (__bf16)W1[(kf * 32 + kg * 8 + j) * DF + col * 4 + nt];
    }

    // ---- pipeline prologue: cold-load first batch's (nbr, y) ----
    const int efirst = e_begin + wv * 64 + lane;
    int   nb_cur = 0;
    float ya0 = 0.f, ya1 = 0.f, ya2 = 0.f;
    if (efirst < e_end) {
        nb_cur = nbr[efirst];
        ya0 = y[nb_cur * 3 + 0]; ya1 = y[nb_cur * 3 + 1]; ya2 = y[nb_cur * 3 + 2];
    }

    __bf16* const hw = &hL[wv][0][0];
    const int swz = (col & 7) << 4;

    auto ldfv = [&](int packed) -> float4 {
        return *(const float4*)(fy + (packed >> 5) * DF + col * 4);
    };

    // ---- barrier-free main loop: each wave owns 64-edge batches, stride 256 ----
    for (int ebase = e_begin + wv * 64; ebase < e_end; ebase += 256) {
        const int e = ebase + lane;

        int sg = 0;
        #pragma unroll
        for (int step = 16; step >= 1; step >>= 1)
            if (splitsL[sg + step] <= e) sg += step;
        sg = min(sg, NPB - 1);

        nsL[wv][lane] = (nb_cur << 5) | sg;
        bf16x8 ag = {};
        if (e < e_end) {
            ag[0] = (__bf16)ya0; ag[1] = (__bf16)ya1; ag[2] = (__bf16)ya2;
            ag[3] = (__bf16)yselfL[sg][0];
            ag[4] = (__bf16)yselfL[sg][1];
            ag[5] = (__bf16)yselfL[sg][2];
            ag[6] = (__bf16)1.0f;            // bias slot (W0ext row 6 = b0)
        }
        *(bf16x8*)&aggW[wv][lane][0] = ag;

        // prefetch next batch's neighbor index
        const int en = e + 256;
        int nb_nxt = 0;
        if (en < e_end) nb_nxt = nbr[en];

        // ---- prefetch group 0's (q, fy rows) ----
        int4 q = *(const int4*)&nsL[wv][kg * 4];
        float4 f0 = ldfv(q.x), f1 = ldfv(q.y), f2 = ldfv(q.z), f3 = ldfv(q.w);

        #pragma unroll
        for (int g = 0; g < 4; g++) {
            // ---- issue group g+1's q + fy prefetches (hide under this group's compute) ----
            int4 qn = q; float4 f0n = f0, f1n = f1, f2n = f2, f3n = f3;
            if (g < 3) {
                qn = *(const int4*)&nsL[wv][(g + 1) * 16 + kg * 4];
                f0n = ldfv(qn.x); f1n = ldfv(qn.y); f2n = ldfv(qn.z); f3n = ldfv(qn.w);
            }

            const int gb = g * 16;
            bf16x8 a0 = {};
            if (kg == 0) a0 = *(const bf16x8*)&aggW[wv][gb + col][0];

            // layer 0 SWAPPED: lane holds h0^T[feat nt*16+kg*4+r][edge=col]
            f32x4 acc0[4] = {};
            #pragma unroll
            for (int nt = 0; nt < 4; nt++)
                acc0[nt] = __builtin_amdgcn_mfma_f32_16x16x32_bf16(w0f[nt], a0, acc0[nt], 0, 0, 0);

            // gelu + pack + 4x ds_write_b64 into hL[edge=col][feature] (swizzled)
            #pragma unroll
            for (int nt = 0; nt < 4; nt++) {
                const unsigned p0 = cvt_pk_bf16(gelu_f(acc0[nt][0]), gelu_f(acc0[nt][1]));
                const unsigned p1 = cvt_pk_bf16(gelu_f(acc0[nt][2]), gelu_f(acc0[nt][3]));
                const int off = col * 128 + ((nt * 32 + kg * 8) ^ swz);
                *(int2*)((char*)hw + off) = make_int2((int)p0, (int)p1);
            }
            bf16x8 af1[2];
            #pragma unroll
            for (int kf = 0; kf < 2; kf++) {
                const int off = col * 128 + ((kf * 64 + kg * 16) ^ swz);
                af1[kf] = *(const bf16x8*)((const char*)hw + off);
            }

            // layer 1: D1[edge=kg*4+r][c=col*4+nt], fp32 accum
            f32x4 acc[4] = {};
            #pragma unroll
            for (int nt = 0; nt < 4; nt++) {
                acc[nt] = __builtin_amdgcn_mfma_f32_16x16x32_bf16(af1[0], w1f[nt][0], acc[nt], 0, 0, 0);
                acc[nt] = __builtin_amdgcn_mfma_f32_16x16x32_bf16(af1[1], w1f[nt][1], acc[nt], 0, 0, 0);
            }

            // gate by prefetched fy rows, segmented-reduce into LDS node accumulators
            const int s0 = q.x & 31, s1 = q.y & 31, s2 = q.z & 31, s3 = q.w & 31;
            const int rem = e_end - (ebase + gb + kg * 4);   // edge r valid iff r < rem
            #pragma unroll
            for (int nt = 0; nt < 4; nt++) {
                const int   c  = col * 4 + nt;
                const float bb = b1r[nt];
                float v0 = (0 < rem) ? (acc[nt][0] + bb) * (&f0.x)[nt] : 0.0f;
                float v1 = (1 < rem) ? (acc[nt][1] + bb) * (&f1.x)[nt] : 0.0f;
                float v2 = (2 < rem) ? (acc[nt][2] + bb) * (&f2.x)[nt] : 0.0f;
                float v3 = (3 < rem) ? (acc[nt][3] + bb) * (&f3.x)[nt] : 0.0f;
                if (s0 == s3) {   // monotone seg -> all four equal: merged single atomic
                    unsafeAtomicAdd(&nodeacc[s0][c], ((v0 + v1) + (v2 + v3)));
                } else {
                    unsafeAtomicAdd(&nodeacc[s0][c], v0);
                    unsafeAtomicAdd(&nodeacc[s1][c], v1);
                    unsafeAtomicAdd(&nodeacc[s2][c], v2);
                    unsafeAtomicAdd(&nodeacc[s3][c], v3);
                }
            }

            // mid-iter: gather next batch's y (nb_nxt landed under groups 0-1)
            if (g == 1) {
                ya0 = ya1 = ya2 = 0.f;
                if (en < e_end) {
                    ya0 = y[nb_nxt * 3 + 0]; ya1 = y[nb_nxt * 3 + 1]; ya2 = y[nb_nxt * 3 + 2];
                }
                nb_cur = nb_nxt;
            }

            q = qn; f0 = f0n; f1 = f1n; f2 = f2n; f3 = f3n;
        }
    }

    __syncthreads();

    // ---- Epilogue: mean and store (each node owned by exactly this block) ----
    for (int i = t; i < NPB * (DF / 4); i += 256) {
        const int node = i >> 4;
        const int cnt  = splitsL[node + 1] - splitsL[node];
        const float inv = (cnt > 0) ? __fdividef(1.0f, (float)cnt) : 0.0f;
        float4 v = ((const float4*)nodeacc)[i];
        v.x *= inv; v.y *= inv; v.z *= inv; v.w *= inv;
        ((float4*)out)[n0 * (DF / 4) + i] = v;
    }
}

extern "C" void kernel_launch(void* const* d_in, const int* in_sizes, int n_in,
                              void* d_out, int out_size, void* d_ws, size_t ws_size,
                              hipStream_t stream) {
    const float* y   = (const float*)d_in[0];
    const float* fyv = (const float*)d_in[1];
    const float* W0  = (const float*)d_in[2];
    const float* b0  = (const float*)d_in[3];
    const float* W1  = (const float*)d_in[4];
    const float* b1  = (const float*)d_in[5];
    const int*   nb  = (const int*)d_in[6];   // harness delivers integer inputs as int32
    const int*   sp  = (const int*)d_in[7];
    it_fused<<<NBLK, 256, 0, stream>>>(y, fyv, W0, b0, W1, b1, nb, sp, (float*)d_out);
}

// Round 11
// 249.479 us; speedup vs baseline: 1.0922x; 1.0857x over previous
//
#include <hip/hip_runtime.h>
#include <hip/hip_bf16.h>

#define NN    100000
#define DF    64
#define NPB   32
#define NBLK  (NN / NPB)   // 3125 exact

typedef __bf16 bf16x8 __attribute__((ext_vector_type(8)));
typedef float  f32x4  __attribute__((ext_vector_type(4)));

// tanh-approx gelu, exp2-folded: x / (1 + 2^-(c1*x + c2*x^3))
__device__ __forceinline__ float gelu_f(float x) {
    float u2 = x * (2.302234849f + 0.102953097f * x * x);
    float s  = exp2f(-u2);
    return __fdividef(x, 1.0f + s);
}

__device__ __forceinline__ unsigned cvt_pk_bf16(float lo, float hi) {
    unsigned r;
    asm("v_cvt_pk_bf16_f32 %0, %1, %2" : "=v"(r) : "v"(lo), "v"(hi));
    return r;
}

// (256,3): register budget 512/3 ~= 170 — room for the cross-group prefetch
// state WITHOUT spill. Measured occupancy has been ~3 waves/SIMD at every
// tighter cap, so this costs nothing.
__global__ __launch_bounds__(256, 3)
void it_fused(const float* __restrict__ y, const float* __restrict__ fy,
              const float* __restrict__ W0, const float* __restrict__ b0,
              const float* __restrict__ W1, const float* __restrict__ b1,
              const int* __restrict__ nbr, const int* __restrict__ splits,
              float* __restrict__ out)
{
    __shared__ int   splitsL[NPB + 1];
    __shared__ float yselfL[NPB][3];
    __shared__ float nodeacc[NPB + 1][DF];                   // +1 dummy row for tail edges
    __shared__ __align__(16) int nsL[4][64];                 // packed nb*64+sg
    __shared__ __align__(16) __bf16 aggW[4][64][8];
    __shared__ __align__(16) __bf16 hL[4][16][DF];

    const int t  = threadIdx.x;
    const int n0 = blockIdx.x * NPB;

    if (t <= NPB) splitsL[t] = splits[n0 + t];
    if (t < NPB) {
        yselfL[t][0] = y[(n0 + t) * 3 + 0];
        yselfL[t][1] = y[(n0 + t) * 3 + 1];
        yselfL[t][2] = y[(n0 + t) * 3 + 2];
    }
    for (int i = t; i < (NPB + 1) * DF / 4; i += 256)
        ((float4*)nodeacc)[i] = make_float4(0, 0, 0, 0);
    __syncthreads();

    const int e_begin = splitsL[0];
    const int e_end   = splitsL[NPB];
    const int lane = t & 63;
    const int wv   = t >> 6;
    const int col  = lane & 15;
    const int kg   = lane >> 4;

    // ---- weight fragments (register-resident) ----
    bf16x8 w0f[4];
    #pragma unroll
    for (int nt = 0; nt < 4; nt++)
        #pragma unroll
        for (int j = 0; j < 8; j++) {
            const int k = kg * 8 + j;
            float v = 0.0f;
            if (k < 6)       v = W0[k * DF + nt * 16 + col];
            else if (k == 6) v = b0[nt * 16 + col];
            w0f[nt][j] = (__bf16)v;
        }
    bf16x8 w1f[4][2];
    float  b1r[4];
    #pragma unroll
    for (int nt = 0; nt < 4; nt++) {
        b1r[nt] = b1[col * 4 + nt];
        #pragma unroll
        for (int kf = 0; kf < 2; kf++)
            #pragma unroll
            for (int j = 0; j < 8; j++)
                w1f[nt][kf][j] = (__bf16)W1[(kf * 32 + kg * 8 + j) * DF + col * 4 + nt];
    }

    // ---- pipeline prologue: cold-load first batch's (nbr, y) ----
    const int efirst = e_begin + wv * 64 + lane;
    int   nb_cur = 0;
    float ya0 = 0.f, ya1 = 0.f, ya2 = 0.f;
    if (efirst < e_end) {
        nb_cur = nbr[efirst];
        ya0 = y[nb_cur * 3 + 0]; ya1 = y[nb_cur * 3 + 1]; ya2 = y[nb_cur * 3 + 2];
    }

    __bf16* const hw = &hL[wv][0][0];
    const int swz = (col & 7) << 4;

    auto ldfv = [&](int packed) -> float4 {
        return *(const float4*)(fy + (packed >> 6) * DF + col * 4);
    };

    // ---- barrier-free main loop: each wave owns 64-edge batches, stride 256 ----
    for (int ebase = e_begin + wv * 64; ebase < e_end; ebase += 256) {
        const int e = ebase + lane;

        int sg = 0;
        #pragma unroll
        for (int step = 16; step >= 1; step >>= 1)
            if (splitsL[sg + step] <= e) sg += step;
        sg = (e < e_end) ? min(sg, NPB - 1) : NPB;     // tail edges -> dummy row

        nsL[wv][lane] = (nb_cur << 6) | sg;
        bf16x8 ag = {};
        if (e < e_end) {
            ag[0] = (__bf16)ya0; ag[1] = (__bf16)ya1; ag[2] = (__bf16)ya2;
            ag[3] = (__bf16)yselfL[sg][0];
            ag[4] = (__bf16)yselfL[sg][1];
            ag[5] = (__bf16)yselfL[sg][2];
            ag[6] = (__bf16)1.0f;            // bias slot (W0ext row 6 = b0)
        }
        *(bf16x8*)&aggW[wv][lane][0] = ag;

        // prefetch next batch's neighbor index
        const int en = e + 256;
        int nb_nxt = 0;
        if (en < e_end) nb_nxt = nbr[en];

        // ---- prefetch group 0's inputs ----
        int4 q = *(const int4*)&nsL[wv][kg * 4];
        bf16x8 a0 = {};
        if (kg == 0) a0 = *(const bf16x8*)&aggW[wv][col][0];
        float4 f0 = ldfv(q.x), f1 = ldfv(q.y), f2 = ldfv(q.z), f3 = ldfv(q.w);

        #pragma unroll
        for (int g = 0; g < 4; g++) {
            // ---- issue group g+1's prefetches (hide under this group's compute) ----
            int4 qn = q; bf16x8 an = {}; float4 f0n = f0, f1n = f1, f2n = f2, f3n = f3;
            if (g < 3) {
                qn = *(const int4*)&nsL[wv][(g + 1) * 16 + kg * 4];
                if (kg == 0) an = *(const bf16x8*)&aggW[wv][(g + 1) * 16 + col][0];
                f0n = ldfv(qn.x); f1n = ldfv(qn.y); f2n = ldfv(qn.z); f3n = ldfv(qn.w);
            }

            // layer 0 SWAPPED: lane holds h0^T[feat nt*16+kg*4+r][edge=col]
            f32x4 acc0[4] = {};
            #pragma unroll
            for (int nt = 0; nt < 4; nt++)
                acc0[nt] = __builtin_amdgcn_mfma_f32_16x16x32_bf16(w0f[nt], a0, acc0[nt], 0, 0, 0);

            // gelu + pack + 4x ds_write_b64 into hL[edge=col][feature] (swizzled)
            #pragma unroll
            for (int nt = 0; nt < 4; nt++) {
                const unsigned p0 = cvt_pk_bf16(gelu_f(acc0[nt][0]), gelu_f(acc0[nt][1]));
                const unsigned p1 = cvt_pk_bf16(gelu_f(acc0[nt][2]), gelu_f(acc0[nt][3]));
                const int off = col * 128 + ((nt * 32 + kg * 8) ^ swz);
                *(int2*)((char*)hw + off) = make_int2((int)p0, (int)p1);
            }
            bf16x8 af1[2];
            #pragma unroll
            for (int kf = 0; kf < 2; kf++) {
                const int off = col * 128 + ((kf * 64 + kg * 16) ^ swz);
                af1[kf] = *(const bf16x8*)((const char*)hw + off);
            }

            // layer 1: D1[edge=kg*4+r][c=col*4+nt], fp32 accum
            f32x4 acc[4] = {};
            #pragma unroll
            for (int nt = 0; nt < 4; nt++) {
                acc[nt] = __builtin_amdgcn_mfma_f32_16x16x32_bf16(af1[0], w1f[nt][0], acc[nt], 0, 0, 0);
                acc[nt] = __builtin_amdgcn_mfma_f32_16x16x32_bf16(af1[1], w1f[nt][1], acc[nt], 0, 0, 0);
            }

            // gate by prefetched fy rows, segmented-reduce (dummy row absorbs tail)
            const int s0 = q.x & 63, s1 = q.y & 63, s2 = q.z & 63, s3 = q.w & 63;
            #pragma unroll
            for (int nt = 0; nt < 4; nt++) {
                const int   c  = col * 4 + nt;
                const float bb = b1r[nt];
                const float v0 = (acc[nt][0] + bb) * ((const float*)&f0)[nt];
                const float v1 = (acc[nt][1] + bb) * ((const float*)&f1)[nt];
                const float v2 = (acc[nt][2] + bb) * ((const float*)&f2)[nt];
                const float v3 = (acc[nt][3] + bb) * ((const float*)&f3)[nt];
                if (s0 == s3) {   // monotone seg -> all four equal: merged single atomic
                    unsafeAtomicAdd(&nodeacc[s0][c], ((v0 + v1) + (v2 + v3)));
                } else {
                    unsafeAtomicAdd(&nodeacc[s0][c], v0);
                    unsafeAtomicAdd(&nodeacc[s1][c], v1);
                    unsafeAtomicAdd(&nodeacc[s2][c], v2);
                    unsafeAtomicAdd(&nodeacc[s3][c], v3);
                }
            }

            // mid-iter: gather next batch's y (nb_nxt landed under groups 0-1)
            if (g == 1) {
                ya0 = ya1 = ya2 = 0.f;
                if (en < e_end) {
                    ya0 = y[nb_nxt * 3 + 0]; ya1 = y[nb_nxt * 3 + 1]; ya2 = y[nb_nxt * 3 + 2];
                }
                nb_cur = nb_nxt;
            }

            q = qn; a0 = an; f0 = f0n; f1 = f1n; f2 = f2n; f3 = f3n;
        }
    }

    __syncthreads();

    // ---- Epilogue: mean and store (each node owned by exactly this block) ----
    for (int i = t; i < NPB * (DF / 4); i += 256) {
        const int node = i >> 4;
        const int cnt  = splitsL[node + 1] - splitsL[node];
        const float inv = (cnt > 0) ? __fdividef(1.0f, (float)cnt) : 0.0f;
        float4 v = ((const float4*)nodeacc)[i];
        v.x *= inv; v.y *= inv; v.z *= inv; v.w *= inv;
        ((float4*)out)[n0 * (DF / 4) + i] = v;
    }
}

extern "C" void kernel_launch(void* const* d_in, const int* in_sizes, int n_in,
                              void* d_out, int out_size, void* d_ws, size_t ws_size,
                              hipStream_t stream) {
    const float* y   = (const float*)d_in[0];
    const float* fyv = (const float*)d_in[1];
    const float* W0  = (const float*)d_in[2];
    const float* b0  = (const float*)d_in[3];
    const float* W1  = (const float*)d_in[4];
    const float* b1  = (const float*)d_in[5];
    const int*   nb  = (const int*)d_in[6];   // harness delivers integer inputs as int32
    const int*   sp  = (const int*)d_in[7];
    it_fused<<<NBLK, 256, 0, stream>>>(y, fyv, W0, b0, W1, b1, nb, sp, (float*)d_out);
}

// Round 12
// 222.807 us; speedup vs baseline: 1.2229x; 1.1197x over previous
//
#include <hip/hip_runtime.h>
#include <hip/hip_bf16.h>

#define NN    100000
#define EE    1600000
#define DF    64
#define NPB   32
#define NBLK  (NN / NPB)   // 3125 exact

typedef __bf16 bf16x8 __attribute__((ext_vector_type(8)));
typedef float  f32x4  __attribute__((ext_vector_type(4)));

// tanh-approx gelu, exp2-folded: x / (1 + 2^-(c1*x + c2*x^3))
__device__ __forceinline__ float gelu_f(float x) {
    float u2 = x * (2.302234849f + 0.102953097f * x * x);
    float s  = exp2f(-u2);
    return __fdividef(x, 1.0f + s);
}

__device__ __forceinline__ unsigned cvt_pk_bf16(float lo, float hi) {
    unsigned r;
    asm("v_cvt_pk_bf16_f32 %0, %1, %2" : "=v"(r) : "v"(lo), "v"(hi));
    return r;
}

// ============================ two-pass path ============================

// ---- kernel 0: seg[e] = node owning edge e (CSR inverse) ----
__global__ void it_seg(const int* __restrict__ splits, int* __restrict__ seg) {
    const int n = blockIdx.x * 256 + threadIdx.x;
    if (n < NN) {
        const int s0 = splits[n], s1 = splits[n + 1];
        for (int e = s0; e < s1; ++e) seg[e] = n;
    }
}

// ---- kernel 1: per-edge MLP, h[e][c] = (gelu(agg@W0+b0)@W1 + b1) * fy[nbr[e]][c] ----
__global__ __launch_bounds__(256, 4)
void it_edge(const float* __restrict__ y, const float* __restrict__ fy,
             const float* __restrict__ W0, const float* __restrict__ b0,
             const float* __restrict__ W1, const float* __restrict__ b1,
             const int* __restrict__ nbr, const int* __restrict__ seg,
             __bf16* __restrict__ h)
{
    __shared__ __align__(16) int    nbL[4][64];
    __shared__ __align__(16) __bf16 aggW[4][64][8];
    __shared__ __align__(16) __bf16 hL[4][16][DF];

    const int t    = threadIdx.x;
    const int lane = t & 63;
    const int wv   = t >> 6;
    const int col  = lane & 15;
    const int kg   = lane >> 4;

    // ---- weight fragments (register-resident; validated layout from R7) ----
    bf16x8 w0f[4];
    #pragma unroll
    for (int nt = 0; nt < 4; nt++)
        #pragma unroll
        for (int j = 0; j < 8; j++) {
            const int k = kg * 8 + j;
            float v = 0.0f;
            if (k < 6)       v = W0[k * DF + nt * 16 + col];
            else if (k == 6) v = b0[nt * 16 + col];
            w0f[nt][j] = (__bf16)v;
        }
    bf16x8 w1f[4][2];
    float  b1r[4];
    #pragma unroll
    for (int nt = 0; nt < 4; nt++) {
        b1r[nt] = b1[col * 4 + nt];
        #pragma unroll
        for (int kf = 0; kf < 2; kf++)
            #pragma unroll
            for (int j = 0; j < 8; j++)
                w1f[nt][kf][j] = (__bf16)W1[(kf * 32 + kg * 8 + j) * DF + col * 4 + nt];
    }

    // ---- stage this wave's 64 edges (E = grid*256 exactly, no tail) ----
    const int ebase = blockIdx.x * 256 + wv * 64;
    const int e     = ebase + lane;
    const int nb    = nbr[e];
    const int sge   = seg[e];
    nbL[wv][lane] = nb;
    bf16x8 ag = {};
    ag[0] = (__bf16)y[nb * 3 + 0];
    ag[1] = (__bf16)y[nb * 3 + 1];
    ag[2] = (__bf16)y[nb * 3 + 2];
    ag[3] = (__bf16)y[sge * 3 + 0];
    ag[4] = (__bf16)y[sge * 3 + 1];
    ag[5] = (__bf16)y[sge * 3 + 2];
    ag[6] = (__bf16)1.0f;               // bias slot (W0ext row 6 = b0)
    *(bf16x8*)&aggW[wv][lane][0] = ag;

    __bf16* const hw = &hL[wv][0][0];
    const int swz = (col & 7) << 4;

    #pragma unroll
    for (int g = 0; g < 4; g++) {
        const int gb = g * 16;
        const int4 q = *(const int4*)&nbL[wv][gb + kg * 4];

        bf16x8 a0 = {};
        if (kg == 0) a0 = *(const bf16x8*)&aggW[wv][gb + col][0];

        // layer 0 SWAPPED: lane holds h0^T[feat nt*16+kg*4+r][edge=col]
        f32x4 acc0[4] = {};
        #pragma unroll
        for (int nt = 0; nt < 4; nt++)
            acc0[nt] = __builtin_amdgcn_mfma_f32_16x16x32_bf16(w0f[nt], a0, acc0[nt], 0, 0, 0);

        // gelu + pack + 4x ds_write_b64 into hL[edge=col][feature] (swizzled)
        #pragma unroll
        for (int nt = 0; nt < 4; nt++) {
            const unsigned p0 = cvt_pk_bf16(gelu_f(acc0[nt][0]), gelu_f(acc0[nt][1]));
            const unsigned p1 = cvt_pk_bf16(gelu_f(acc0[nt][2]), gelu_f(acc0[nt][3]));
            const int off = col * 128 + ((nt * 32 + kg * 8) ^ swz);
            *(int2*)((char*)hw + off) = make_int2((int)p0, (int)p1);
        }
        bf16x8 af1[2];
        #pragma unroll
        for (int kf = 0; kf < 2; kf++) {
            const int off = col * 128 + ((kf * 64 + kg * 16) ^ swz);
            af1[kf] = *(const bf16x8*)((const char*)hw + off);
        }

        // layer 1: D1[edge=kg*4+r][c=col*4+nt], fp32 accum
        f32x4 acc[4] = {};
        #pragma unroll
        for (int nt = 0; nt < 4; nt++) {
            acc[nt] = __builtin_amdgcn_mfma_f32_16x16x32_bf16(af1[0], w1f[nt][0], acc[nt], 0, 0, 0);
            acc[nt] = __builtin_amdgcn_mfma_f32_16x16x32_bf16(af1[1], w1f[nt][1], acc[nt], 0, 0, 0);
        }

        // gate by fy row, pack 4 bf16, coalesced 8B store per edge-row
        #pragma unroll
        for (int r = 0; r < 4; r++) {
            const int qq = (&q.x)[r];
            const float4 fv = *(const float4*)(fy + (size_t)qq * DF + col * 4);
            const unsigned u0 = cvt_pk_bf16((acc[0][r] + b1r[0]) * fv.x,
                                            (acc[1][r] + b1r[1]) * fv.y);
            const unsigned u1 = cvt_pk_bf16((acc[2][r] + b1r[2]) * fv.z,
                                            (acc[3][r] + b1r[3]) * fv.w);
            const size_t er = (size_t)(ebase + gb + kg * 4 + r);
            *(int2*)((char*)h + er * 128 + col * 8) = make_int2((int)u0, (int)u1);
        }
    }
}

// ---- kernel 2: per-node mean over CSR range (one wave per node) ----
__global__ void it_reduce(const int* __restrict__ splits,
                          const __bf16* __restrict__ h,
                          float* __restrict__ out)
{
    const int t    = threadIdx.x;
    const int lane = t & 63;
    const int wv   = t >> 6;
    const int n    = blockIdx.x * 4 + wv;          // grid*4 == NN exactly
    const int s0 = splits[n], s1 = splits[n + 1];
    const int par = lane >> 5, cp = lane & 31;     // 2 rows per pass, u32 per lane

    float a0 = 0.f, a1 = 0.f;
    for (int e = s0 + par; e < s1; e += 2) {
        const unsigned u = *(const unsigned*)((const char*)h + (size_t)e * 128 + cp * 4);
        a0 += __uint_as_float(u << 16);            // col 2cp
        a1 += __uint_as_float(u & 0xffff0000u);    // col 2cp+1
    }
    a0 += __shfl_xor(a0, 32);
    a1 += __shfl_xor(a1, 32);
    const int cnt = s1 - s0;
    const float inv = (cnt > 0) ? __fdividef(1.0f, (float)cnt) : 0.0f;
    if (lane < 32) {
        float2 v; v.x = a0 * inv; v.y = a1 * inv;
        *(float2*)(out + (size_t)n * DF + cp * 2) = v;
    }
}

// ============================ fallback path (validated R11 kernel) ============================

__global__ __launch_bounds__(256, 3)
void it_fused(const float* __restrict__ y, const float* __restrict__ fy,
              const float* __restrict__ W0, const float* __restrict__ b0,
              const float* __restrict__ W1, const float* __restrict__ b1,
              const int* __restrict__ nbr, const int* __restrict__ splits,
              float* __restrict__ out)
{
    __shared__ int   splitsL[NPB + 1];
    __shared__ float yselfL[NPB][3];
    __shared__ float nodeacc[NPB + 1][DF];
    __shared__ __align__(16) int nsL[4][64];
    __shared__ __align__(16) __bf16 aggW[4][64][8];
    __shared__ __align__(16) __bf16 hL[4][16][DF];

    const int t  = threadIdx.x;
    const int n0 = blockIdx.x * NPB;

    if (t <= NPB) splitsL[t] = splits[n0 + t];
    if (t < NPB) {
        yselfL[t][0] = y[(n0 + t) * 3 + 0];
        yselfL[t][1] = y[(n0 + t) * 3 + 1];
        yselfL[t][2] = y[(n0 + t) * 3 + 2];
    }
    for (int i = t; i < (NPB + 1) * DF / 4; i += 256)
        ((float4*)nodeacc)[i] = make_float4(0, 0, 0, 0);
    __syncthreads();

    const int e_begin = splitsL[0];
    const int e_end   = splitsL[NPB];
    const int lane = t & 63;
    const int wv   = t >> 6;
    const int col  = lane & 15;
    const int kg   = lane >> 4;

    bf16x8 w0f[4];
    #pragma unroll
    for (int nt = 0; nt < 4; nt++)
        #pragma unroll
        for (int j = 0; j < 8; j++) {
            const int k = kg * 8 + j;
            float v = 0.0f;
            if (k < 6)       v = W0[k * DF + nt * 16 + col];
            else if (k == 6) v = b0[nt * 16 + col];
            w0f[nt][j] = (__bf16)v;
        }
    bf16x8 w1f[4][2];
    float  b1r[4];
    #pragma unroll
    for (int nt = 0; nt < 4; nt++) {
        b1r[nt] = b1[col * 4 + nt];
        #pragma unroll
        for (int kf = 0; kf < 2; kf++)
            #pragma unroll
            for (int j = 0; j < 8; j++)
                w1f[nt][kf][j] = (__bf16)W1[(kf * 32 + kg * 8 + j) * DF + col * 4 + nt];
    }

    const int efirst = e_begin + wv * 64 + lane;
    int   nb_cur = 0;
    float ya0 = 0.f, ya1 = 0.f, ya2 = 0.f;
    if (efirst < e_end) {
        nb_cur = nbr[efirst];
        ya0 = y[nb_cur * 3 + 0]; ya1 = y[nb_cur * 3 + 1]; ya2 = y[nb_cur * 3 + 2];
    }

    __bf16* const hw = &hL[wv][0][0];
    const int swz = (col & 7) << 4;

    auto ldfv = [&](int packed) -> float4 {
        return *(const float4*)(fy + (packed >> 6) * DF + col * 4);
    };

    for (int ebase = e_begin + wv * 64; ebase < e_end; ebase += 256) {
        const int e = ebase + lane;

        int sg = 0;
        #pragma unroll
        for (int step = 16; step >= 1; step >>= 1)
            if (splitsL[sg + step] <= e) sg += step;
        sg = (e < e_end) ? min(sg, NPB - 1) : NPB;

        nsL[wv][lane] = (nb_cur << 6) | sg;
        bf16x8 ag = {};
        if (e < e_end) {
            ag[0] = (__bf16)ya0; ag[1] = (__bf16)ya1; ag[2] = (__bf16)ya2;
            ag[3] = (__bf16)yselfL[sg][0];
            ag[4] = (__bf16)yselfL[sg][1];
            ag[5] = (__bf16)yselfL[sg][2];
            ag[6] = (__bf16)1.0f;
        }
        *(bf16x8*)&aggW[wv][lane][0] = ag;

        const int en = e + 256;
        int nb_nxt = 0;
        if (en < e_end) nb_nxt = nbr[en];

        int4 q = *(const int4*)&nsL[wv][kg * 4];
        bf16x8 a0 = {};
        if (kg == 0) a0 = *(const bf16x8*)&aggW[wv][col][0];
        float4 f0 = ldfv(q.x), f1 = ldfv(q.y), f2 = ldfv(q.z), f3 = ldfv(q.w);

        #pragma unroll
        for (int g = 0; g < 4; g++) {
            int4 qn = q; bf16x8 an = {}; float4 f0n = f0, f1n = f1, f2n = f2, f3n = f3;
            if (g < 3) {
                qn = *(const int4*)&nsL[wv][(g + 1) * 16 + kg * 4];
                if (kg == 0) an = *(const bf16x8*)&aggW[wv][(g + 1) * 16 + col][0];
                f0n = ldfv(qn.x); f1n = ldfv(qn.y); f2n = ldfv(qn.z); f3n = ldfv(qn.w);
            }

            f32x4 acc0[4] = {};
            #pragma unroll
            for (int nt = 0; nt < 4; nt++)
                acc0[nt] = __builtin_amdgcn_mfma_f32_16x16x32_bf16(w0f[nt], a0, acc0[nt], 0, 0, 0);

            #pragma unroll
            for (int nt = 0; nt < 4; nt++) {
                const unsigned p0 = cvt_pk_bf16(gelu_f(acc0[nt][0]), gelu_f(acc0[nt][1]));
                const unsigned p1 = cvt_pk_bf16(gelu_f(acc0[nt][2]), gelu_f(acc0[nt][3]));
                const int off = col * 128 + ((nt * 32 + kg * 8) ^ swz);
                *(int2*)((char*)hw + off) = make_int2((int)p0, (int)p1);
            }
            bf16x8 af1[2];
            #pragma unroll
            for (int kf = 0; kf < 2; kf++) {
                const int off = col * 128 + ((kf * 64 + kg * 16) ^ swz);
                af1[kf] = *(const bf16x8*)((const char*)hw + off);
            }

            f32x4 acc[4] = {};
            #pragma unroll
            for (int nt = 0; nt < 4; nt++) {
                acc[nt] = __builtin_amdgcn_mfma_f32_16x16x32_bf16(af1[0], w1f[nt][0], acc[nt], 0, 0, 0);
                acc[nt] = __builtin_amdgcn_mfma_f32_16x16x32_bf16(af1[1], w1f[nt][1], acc[nt], 0, 0, 0);
            }

            const int s0 = q.x & 63, s1 = q.y & 63, s2 = q.z & 63, s3 = q.w & 63;
            #pragma unroll
            for (int nt = 0; nt < 4; nt++) {
                const int   c  = col * 4 + nt;
                const float bb = b1r[nt];
                const float v0 = (acc[nt][0] + bb) * ((const float*)&f0)[nt];
                const float v1 = (acc[nt][1] + bb) * ((const float*)&f1)[nt];
                const float v2 = (acc[nt][2] + bb) * ((const float*)&f2)[nt];
                const float v3 = (acc[nt][3] + bb) * ((const float*)&f3)[nt];
                if (s0 == s3) {
                    unsafeAtomicAdd(&nodeacc[s0][c], ((v0 + v1) + (v2 + v3)));
                } else {
                    unsafeAtomicAdd(&nodeacc[s0][c], v0);
                    unsafeAtomicAdd(&nodeacc[s1][c], v1);
                    unsafeAtomicAdd(&nodeacc[s2][c], v2);
                    unsafeAtomicAdd(&nodeacc[s3][c], v3);
                }
            }

            if (g == 1) {
                ya0 = ya1 = ya2 = 0.f;
                if (en < e_end) {
                    ya0 = y[nb_nxt * 3 + 0]; ya1 = y[nb_nxt * 3 + 1]; ya2 = y[nb_nxt * 3 + 2];
                }
                nb_cur = nb_nxt;
            }

            q = qn; a0 = an; f0 = f0n; f1 = f1n; f2 = f2n; f3 = f3n;
        }
    }

    __syncthreads();

    for (int i = t; i < NPB * (DF / 4); i += 256) {
        const int node = i >> 4;
        const int cnt  = splitsL[node + 1] - splitsL[node];
        const float inv = (cnt > 0) ? __fdividef(1.0f, (float)cnt) : 0.0f;
        float4 v = ((const float4*)nodeacc)[i];
        v.x *= inv; v.y *= inv; v.z *= inv; v.w *= inv;
        ((float4*)out)[n0 * (DF / 4) + i] = v;
    }
}

// ============================ launcher ============================

extern "C" void kernel_launch(void* const* d_in, const int* in_sizes, int n_in,
                              void* d_out, int out_size, void* d_ws, size_t ws_size,
                              hipStream_t stream) {
    const float* y   = (const float*)d_in[0];
    const float* fyv = (const float*)d_in[1];
    const float* W0  = (const float*)d_in[2];
    const float* b0  = (const float*)d_in[3];
    const float* W1  = (const float*)d_in[4];
    const float* b1  = (const float*)d_in[5];
    const int*   nb  = (const int*)d_in[6];   // harness delivers integer inputs as int32
    const int*   sp  = (const int*)d_in[7];

    const size_t SEG_BYTES = (size_t)EE * 4;              // 6.4 MB
    const size_t H_OFF     = SEG_BYTES;                   // 512-aligned (6.4e6 / 512 exact)
    const size_t H_BYTES   = (size_t)EE * DF * 2;         // 204.8 MB
    if (ws_size >= H_OFF + H_BYTES) {
        int*    seg = (int*)d_ws;
        __bf16* h   = (__bf16*)((char*)d_ws + H_OFF);
        it_seg<<<(NN + 255) / 256, 256, 0, stream>>>(sp, seg);
        it_edge<<<EE / 256, 256, 0, stream>>>(y, fyv, W0, b0, W1, b1, nb, seg, h);
        it_reduce<<<NN / 4, 256, 0, stream>>>(sp, h, (float*)d_out);
    } else {
        it_fused<<<NBLK, 256, 0, stream>>>(y, fyv, W0, b0, W1, b1, nb, sp, (float*)d_out);
    }
}